// Round 1
// baseline (1065.911 us; speedup 1.0000x reference)
//
#include <hip/hip_runtime.h>
#include <math.h>

#define LEAKY 0.01f

// ---------------- utility kernels ----------------

__global__ void k_fill(float* __restrict__ p, float v, int n) {
  int i = blockIdx.x * blockDim.x + threadIdx.x;
  if (i < n) p[i] = v;
}

__global__ void k_deg(const int* __restrict__ dst, float* __restrict__ deg, int E) {
  int i = blockIdx.x * blockDim.x + threadIdx.x;
  if (i < E) atomicAdd(&deg[dst[i]], 1.0f);
}

__global__ void k_rsqrt(float* __restrict__ deg, int n) {
  int i = blockIdx.x * blockDim.x + threadIdx.x;
  if (i < n) deg[i] = rsqrtf(deg[i]);
}

// agg[i,f] = hlin[i,f] * dinv[i]^2   (self-loop contribution)
__global__ void k_self_init(const float* __restrict__ hlin, const float* __restrict__ dinv,
                            float* __restrict__ agg, long total, int F) {
  long i = (long)blockIdx.x * blockDim.x + threadIdx.x;
  if (i < total) {
    int node = (int)(i / F);
    float di = dinv[node];
    agg[i] = hlin[i] * di * di;
  }
}

// one block per edge, blockDim.x == F
__global__ void k_scatter(const int* __restrict__ src, const int* __restrict__ dst,
                          const float* __restrict__ dinv, const float* __restrict__ hlin,
                          float* __restrict__ agg, int E, int F) {
  int e = blockIdx.x;
  int s = src[e];
  int d = dst[e];
  float norm = dinv[s] * dinv[d];
  int f = threadIdx.x;
  atomicAdd(&agg[(long)d * F + f], hlin[(long)s * F + f] * norm);
}

// in-place: agg = leaky(agg + bias); optional second copy to out2
__global__ void k_bias_act(float* __restrict__ agg, const float* __restrict__ bias,
                           float* __restrict__ out2, long total, int F) {
  long i = (long)blockIdx.x * blockDim.x + threadIdx.x;
  if (i < total) {
    int f = (int)(i % F);
    float v = agg[i] + bias[f];
    v = (v > 0.f) ? v : (LEAKY * v);
    agg[i] = v;
    if (out2) out2[i] = v;
  }
}

// ---------------- fp32 tiled GEMM ----------------
// C[M,N] = A[M,K] * B  ;  BT=false: B is [K,N] row-major.  BT=true: C = A * B^T with B [N,K].
// SIG: apply sigmoid to output.
template <bool BT, bool SIG>
__global__ __launch_bounds__(256) void k_gemm(const float* __restrict__ A,
                                              const float* __restrict__ B,
                                              float* __restrict__ C,
                                              int M, int N, int K) {
  const int BM = 64, BN = 64, BK = 32;
  __shared__ float As[BK][68];  // pad to 68 floats: keeps float4 alignment
  __shared__ float Bs[BK][68];

  int tid = threadIdx.x;
  int tx = tid & 15;        // 0..15  -> 4 cols each
  int ty = tid >> 4;        // 0..15  -> 4 rows each
  long bm = (long)blockIdx.y * BM;
  long bn = (long)blockIdx.x * BN;

  float acc[4][4];
#pragma unroll
  for (int i = 0; i < 4; i++)
#pragma unroll
    for (int j = 0; j < 4; j++) acc[i][j] = 0.f;

  for (int k0 = 0; k0 < K; k0 += BK) {
    // load A tile (coalesced along K), store transposed As[k][m]
    for (int i = tid; i < BM * BK; i += 256) {
      int m = i >> 5;       // /BK
      int k = i & 31;
      long gm = bm + m;
      As[k][m] = (gm < M) ? A[gm * K + k0 + k] : 0.f;
    }
    if (BT) {
      // B is [N,K]: load rows of B (coalesced along K), store Bs[k][n]
      for (int i = tid; i < BN * BK; i += 256) {
        int n = i >> 5;
        int k = i & 31;
        long gn = bn + n;
        Bs[k][n] = (gn < N) ? B[gn * K + k0 + k] : 0.f;
      }
    } else {
      // B is [K,N]: coalesced along N
      for (int i = tid; i < BK * BN; i += 256) {
        int k = i >> 6;
        int n = i & 63;
        long gn = bn + n;
        Bs[k][n] = (gn < N) ? B[(long)(k0 + k) * N + gn] : 0.f;
      }
    }
    __syncthreads();

#pragma unroll
    for (int kk = 0; kk < BK; kk++) {
      float4 a4 = *reinterpret_cast<const float4*>(&As[kk][ty * 4]);
      float4 b4 = *reinterpret_cast<const float4*>(&Bs[kk][tx * 4]);
      float av[4] = {a4.x, a4.y, a4.z, a4.w};
      float bv[4] = {b4.x, b4.y, b4.z, b4.w};
#pragma unroll
      for (int i = 0; i < 4; i++)
#pragma unroll
        for (int j = 0; j < 4; j++) acc[i][j] += av[i] * bv[j];
    }
    __syncthreads();
  }

#pragma unroll
  for (int i = 0; i < 4; i++) {
    long gm = bm + ty * 4 + i;
    if (gm >= M) continue;
#pragma unroll
    for (int j = 0; j < 4; j++) {
      long gn = bn + tx * 4 + j;
      if (gn >= N) continue;
      float v = acc[i][j];
      if (SIG) v = 1.f / (1.f + __expf(-v));
      C[gm * N + gn] = v;
    }
  }
}

// ---------------- launch ----------------

extern "C" void kernel_launch(void* const* d_in, const int* in_sizes, int n_in,
                              void* d_out, int out_size, void* d_ws, size_t ws_size,
                              hipStream_t stream) {
  const float* x  = (const float*)d_in[0];
  const int*   ei = (const int*)d_in[1];
  const float* W1 = (const float*)d_in[3];
  const float* b1 = (const float*)d_in[4];
  const float* W2 = (const float*)d_in[5];
  const float* b2 = (const float*)d_in[6];

  const int N   = in_sizes[2];          // 10000 (batch vector length)
  const int E   = in_sizes[1] / 2;      // 320000
  const int Fin = in_sizes[0] / N;      // 512
  const int F1  = in_sizes[4];          // 256
  const int F2  = in_sizes[6];          // 128

  const int* src = ei;
  const int* dst = ei + E;

  float* ws = (float*)d_ws;
  float* dinv   = ws;                       // N floats (padded region 10240)
  float* h1lin  = ws + 10240;               // N*F1
  float* agg1   = h1lin + (long)N * F1;     // N*F1 (becomes h1 in place)
  float* agg2   = agg1 + (long)N * F1;      // N*F2 (becomes h in place)
  float* h2lin  = h1lin;                    // reuse: h1lin dead after scatter1

  float* out_x1 = (float*)d_out;                 // N*N
  float* out_h  = out_x1 + (long)N * N;          // N*F2

  // 1) degrees -> dinv
  k_fill<<<(N + 255) / 256, 256, 0, stream>>>(dinv, 1.0f, N);
  k_deg<<<(E + 255) / 256, 256, 0, stream>>>(dst, dinv, E);
  k_rsqrt<<<(N + 255) / 256, 256, 0, stream>>>(dinv, N);

  // 2) layer 1: h1lin = x @ W1
  {
    dim3 grid((F1 + 63) / 64, (N + 63) / 64);
    k_gemm<false, false><<<grid, 256, 0, stream>>>(x, W1, h1lin, N, F1, Fin);
  }
  {
    long total = (long)N * F1;
    k_self_init<<<(unsigned)((total + 255) / 256), 256, 0, stream>>>(h1lin, dinv, agg1, total, F1);
    k_scatter<<<E, F1, 0, stream>>>(src, dst, dinv, h1lin, agg1, E, F1);
    k_bias_act<<<(unsigned)((total + 255) / 256), 256, 0, stream>>>(agg1, b1, nullptr, total, F1);
  }

  // 3) layer 2: h2lin = h1 @ W2
  {
    dim3 grid((F2 + 63) / 64, (N + 63) / 64);
    k_gemm<false, false><<<grid, 256, 0, stream>>>(agg1, W2, h2lin, N, F2, F1);
  }
  {
    long total = (long)N * F2;
    k_self_init<<<(unsigned)((total + 255) / 256), 256, 0, stream>>>(h2lin, dinv, agg2, total, F2);
    k_scatter<<<E, F2, 0, stream>>>(src, dst, dinv, h2lin, agg2, E, F2);
    // in-place leaky + copy h to d_out tail
    k_bias_act<<<(unsigned)((total + 255) / 256), 256, 0, stream>>>(agg2, b2, out_h, total, F2);
  }

  // 4) decode: x1 = sigmoid(h @ h^T)
  {
    dim3 grid((N + 63) / 64, (N + 63) / 64);
    k_gemm<true, true><<<grid, 256, 0, stream>>>(agg2, agg2, out_x1, N, N, F2);
  }
}

// Round 2
// 363.456 us; speedup vs baseline: 2.9327x; 2.9327x over previous
//
#include <hip/hip_runtime.h>
#include <math.h>

#define LEAKY 0.01f

using short8 = __attribute__((ext_vector_type(8))) short;
using f32x4  = __attribute__((ext_vector_type(4))) float;

__device__ __forceinline__ ushort f2bf(float f) {
  uint u = __float_as_uint(f);
  uint r = (u + 0x7FFFu + ((u >> 16) & 1u)) >> 16;
  return (ushort)r;
}

// ---------------- degree / CSR build ----------------

__global__ void k_zero_i(int* __restrict__ p, int n) {
  int i = blockIdx.x * blockDim.x + threadIdx.x;
  if (i < n) p[i] = 0;
}

__global__ void k_count(const int* __restrict__ dst, int* __restrict__ cnt, int E) {
  int i = blockIdx.x * blockDim.x + threadIdx.x;
  if (i < E) atomicAdd(&cnt[dst[i]], 1);
}

__global__ void k_dinv(const int* __restrict__ cnt, float* __restrict__ dinv, int N) {
  int i = blockIdx.x * blockDim.x + threadIdx.x;
  if (i < N) dinv[i] = rsqrtf((float)cnt[i] + 1.0f);
}

// single block, 1024 threads; N <= 16384. Writes rowstart[0..N] and cursor[0..N-1]
// (cursor aliases the cnt buffer — cnt consumed by this kernel's reads first).
__global__ void k_scan(const int* __restrict__ cnt, int* __restrict__ rowstart,
                       int* __restrict__ cursor, int N, int Etot) {
  __shared__ int part[1024];
  const int t = threadIdx.x;
  const int CH = 16;
  int base = t * CH;
  int local[CH];
  int s = 0;
#pragma unroll
  for (int i = 0; i < CH; i++) {
    int v = (base + i < N) ? cnt[base + i] : 0;
    local[i] = s;
    s += v;
  }
  part[t] = s;
  __syncthreads();
  for (int off = 1; off < 1024; off <<= 1) {
    int add = (t >= off) ? part[t - off] : 0;
    __syncthreads();
    part[t] += add;
    __syncthreads();
  }
  int excl = (t == 0) ? 0 : part[t - 1];
#pragma unroll
  for (int i = 0; i < CH; i++) {
    if (base + i < N) {
      int rs = excl + local[i];
      rowstart[base + i] = rs;
      cursor[base + i] = rs;
    }
  }
  if (t == 0) rowstart[N] = Etot;
}

__global__ void k_csr(const int* __restrict__ src, const int* __restrict__ dst,
                      int* __restrict__ cursor, int* __restrict__ esrc, int E) {
  int i = blockIdx.x * blockDim.x + threadIdx.x;
  if (i < E) {
    int d = dst[i];
    int pos = atomicAdd(&cursor[d], 1);
    esrc[pos] = src[i];
  }
}

// ---------------- gather aggregation (no atomics) ----------------
// one wave per node; F = VL*64 features per node
template <int F, int VL, bool LAST>
__global__ __launch_bounds__(64) void k_agg(const float* __restrict__ hlin,
                                            const float* __restrict__ dinv,
                                            const int* __restrict__ rowstart,
                                            const int* __restrict__ esrc,
                                            const float* __restrict__ bias,
                                            float* __restrict__ aggout,
                                            float* __restrict__ outh,
                                            ushort* __restrict__ hb, int N) {
  const int node = blockIdx.x;
  const int t = threadIdx.x;
  const float di = dinv[node];
  float acc[VL];
  {
    const float* p = hlin + (long)node * F + t * VL;
    if (VL == 4) {
      float4 v = *reinterpret_cast<const float4*>(p);
      acc[0] = v.x; acc[1] = v.y; acc[2] = v.z; acc[3] = v.w;
    } else {
      float2 v = *reinterpret_cast<const float2*>(p);
      acc[0] = v.x; acc[1] = v.y;
    }
#pragma unroll
    for (int i = 0; i < VL; i++) acc[i] *= di * di;
  }
  const int e0 = rowstart[node], e1 = rowstart[node + 1];
  for (int e = e0; e < e1; e++) {
    int s = esrc[e];
    float nm = dinv[s] * di;
    const float* p = hlin + (long)s * F + t * VL;
    if (VL == 4) {
      float4 v = *reinterpret_cast<const float4*>(p);
      acc[0] += v.x * nm; acc[1] += v.y * nm; acc[2] += v.z * nm; acc[3] += v.w * nm;
    } else {
      float2 v = *reinterpret_cast<const float2*>(p);
      acc[0] += v.x * nm; acc[1] += v.y * nm;
    }
  }
#pragma unroll
  for (int i = 0; i < VL; i++) {
    float v = acc[i] + bias[t * VL + i];
    v = (v > 0.f) ? v : (LEAKY * v);
    long idx = (long)node * F + t * VL + i;
    if (!LAST) {
      aggout[idx] = v;
    } else {
      outh[idx] = v;
      hb[idx] = f2bf(v);
    }
  }
}

// ---------------- fp32 tiled GEMM (layers) ----------------
__global__ __launch_bounds__(256) void k_gemm(const float* __restrict__ A,
                                              const float* __restrict__ B,
                                              float* __restrict__ C,
                                              int M, int N, int K) {
  const int BM = 64, BN = 64, BK = 32;
  __shared__ float As[BK][68];
  __shared__ float Bs[BK][68];

  int tid = threadIdx.x;
  int tx = tid & 15;
  int ty = tid >> 4;
  long bm = (long)blockIdx.y * BM;
  long bn = (long)blockIdx.x * BN;

  float acc[4][4];
#pragma unroll
  for (int i = 0; i < 4; i++)
#pragma unroll
    for (int j = 0; j < 4; j++) acc[i][j] = 0.f;

  for (int k0 = 0; k0 < K; k0 += BK) {
    for (int i = tid; i < BM * BK; i += 256) {
      int m = i >> 5;
      int k = i & 31;
      long gm = bm + m;
      As[k][m] = (gm < M) ? A[gm * K + k0 + k] : 0.f;
    }
    for (int i = tid; i < BK * BN; i += 256) {
      int k = i >> 6;
      int n = i & 63;
      long gn = bn + n;
      Bs[k][n] = (gn < N) ? B[(long)(k0 + k) * N + gn] : 0.f;
    }
    __syncthreads();

#pragma unroll
    for (int kk = 0; kk < BK; kk++) {
      float4 a4 = *reinterpret_cast<const float4*>(&As[kk][ty * 4]);
      float4 b4 = *reinterpret_cast<const float4*>(&Bs[kk][tx * 4]);
      float av[4] = {a4.x, a4.y, a4.z, a4.w};
      float bv[4] = {b4.x, b4.y, b4.z, b4.w};
#pragma unroll
      for (int i = 0; i < 4; i++)
#pragma unroll
        for (int j = 0; j < 4; j++) acc[i][j] += av[i] * bv[j];
    }
    __syncthreads();
  }

#pragma unroll
  for (int i = 0; i < 4; i++) {
    long gm = bm + ty * 4 + i;
    if (gm >= M) continue;
#pragma unroll
    for (int j = 0; j < 4; j++) {
      long gn = bn + tx * 4 + j;
      if (gn >= N) continue;
      C[gm * N + gn] = acc[i][j];
    }
  }
}

// ---------------- bf16 MFMA decode: C = sigmoid(H @ H^T) ----------------
// H: [N,128] bf16. 128x128 tile per block, 4 waves, each wave a 64x64 quadrant.
__global__ __launch_bounds__(256) void k_decode(const ushort* __restrict__ Hb,
                                                float* __restrict__ C, int N) {
  __shared__ ushort lds[2 * 128 * 128];  // A tile 32KB + B tile 32KB, XOR-swizzled
  ushort* ldsA = lds;
  ushort* ldsB = lds + 128 * 128;

  const int tid = threadIdx.x;
  const int lane = tid & 63;
  const int wv = tid >> 6;
  const int wr = wv >> 1, wc = wv & 1;
  const long bm = (long)blockIdx.y * 128;
  const long bn = (long)blockIdx.x * 128;

  // stage both tiles: global (row, cb) -> LDS byte row*256 + (cb ^ ((row&7)<<4))
#pragma unroll
  for (int t = 0; t < 2; t++) {
    long rbase = t ? bn : bm;
    ushort* L = t ? ldsB : ldsA;
#pragma unroll
    for (int it = 0; it < 8; it++) {
      int off = it * 4096 + tid * 16;  // linear byte offset in 32KB tile
      int row = off >> 8;
      int cb = off & 255;
      long grow = rbase + row;
      if (grow >= N) grow = N - 1;
      uint4 v = *reinterpret_cast<const uint4*>(&Hb[grow * 128 + (cb >> 1)]);
      int sb = (row << 8) | (cb ^ ((row & 7) << 4));
      *reinterpret_cast<uint4*>((char*)L + sb) = v;
    }
  }
  __syncthreads();

  f32x4 acc[4][4];
#pragma unroll
  for (int i = 0; i < 4; i++)
#pragma unroll
    for (int j = 0; j < 4; j++) acc[i][j] = (f32x4){0.f, 0.f, 0.f, 0.f};

  const int kb = ((lane >> 4) << 4);  // byte offset of this lane's k-chunk within 64B k-step
#pragma unroll
  for (int ks = 0; ks < 4; ks++) {
    short8 af[4], bf[4];
#pragma unroll
    for (int mi = 0; mi < 4; mi++) {
      int row = wr * 64 + mi * 16 + (lane & 15);
      int b = ks * 64 + kb;
      int addr = (row << 8) | (b ^ ((row & 7) << 4));
      af[mi] = *reinterpret_cast<const short8*>((const char*)ldsA + addr);
    }
#pragma unroll
    for (int ni = 0; ni < 4; ni++) {
      int row = wc * 64 + ni * 16 + (lane & 15);
      int b = ks * 64 + kb;
      int addr = (row << 8) | (b ^ ((row & 7) << 4));
      bf[ni] = *reinterpret_cast<const short8*>((const char*)ldsB + addr);
    }
#pragma unroll
    for (int mi = 0; mi < 4; mi++)
#pragma unroll
      for (int ni = 0; ni < 4; ni++)
        acc[mi][ni] = __builtin_amdgcn_mfma_f32_16x16x32_bf16(af[mi], bf[ni], acc[mi][ni], 0, 0, 0);
  }

  // epilogue: C layout col=lane&15, row=(lane>>4)*4+reg
#pragma unroll
  for (int ni = 0; ni < 4; ni++) {
    long col = bn + wc * 64 + ni * 16 + (lane & 15);
    if (col >= N) continue;
#pragma unroll
    for (int mi = 0; mi < 4; mi++) {
      long rbase2 = bm + wr * 64 + mi * 16 + ((lane >> 4) << 2);
#pragma unroll
      for (int j = 0; j < 4; j++) {
        long row = rbase2 + j;
        if (row >= N) continue;
        float v = acc[mi][ni][j];
        v = 1.f / (1.f + __expf(-v));
        __builtin_nontemporal_store(v, &C[row * N + col]);
      }
    }
  }
}

// ---------------- launch ----------------

extern "C" void kernel_launch(void* const* d_in, const int* in_sizes, int n_in,
                              void* d_out, int out_size, void* d_ws, size_t ws_size,
                              hipStream_t stream) {
  const float* x  = (const float*)d_in[0];
  const int*   ei = (const int*)d_in[1];
  const float* W1 = (const float*)d_in[3];
  const float* b1 = (const float*)d_in[4];
  const float* W2 = (const float*)d_in[5];
  const float* b2 = (const float*)d_in[6];

  const int N   = in_sizes[2];
  const int E   = in_sizes[1] / 2;
  const int Fin = in_sizes[0] / N;
  const int F1  = in_sizes[4];   // 256
  const int F2  = in_sizes[6];   // 128

  const int* src = ei;
  const int* dst = ei + E;

  float* ws = (float*)d_ws;
  float*  h1lin    = ws;                          // N*F1 (also reused as h2lin)
  float*  agg1     = ws + 2560000;                // N*F1
  ushort* hb       = (ushort*)(ws + 5120000);     // N*F2 bf16
  float*  dinv     = ws + 5760000;                // N
  int*    cnt      = (int*)(ws + 5770240);        // N (becomes cursor)
  int*    rowstart = (int*)(ws + 5780480);        // N+1
  int*    esrc     = (int*)(ws + 5790976);        // E
  float*  h2lin    = h1lin;

  float* out_x1 = (float*)d_out;
  float* out_h  = out_x1 + (long)N * N;

  // CSR build
  k_zero_i<<<(N + 255) / 256, 256, 0, stream>>>(cnt, N);
  k_count<<<(E + 255) / 256, 256, 0, stream>>>(dst, cnt, E);
  k_dinv<<<(N + 255) / 256, 256, 0, stream>>>(cnt, dinv, N);
  k_scan<<<1, 1024, 0, stream>>>(cnt, rowstart, cnt, N, E);
  k_csr<<<(E + 255) / 256, 256, 0, stream>>>(src, dst, cnt, esrc, E);

  // layer 1
  {
    dim3 grid((F1 + 63) / 64, (N + 63) / 64);
    k_gemm<<<grid, 256, 0, stream>>>(x, W1, h1lin, N, F1, Fin);
  }
  k_agg<256, 4, false><<<N, 64, 0, stream>>>(h1lin, dinv, rowstart, esrc, b1,
                                             agg1, nullptr, nullptr, N);
  // layer 2
  {
    dim3 grid((F2 + 63) / 64, (N + 63) / 64);
    k_gemm<<<grid, 256, 0, stream>>>(agg1, W2, h2lin, N, F2, F1);
  }
  k_agg<128, 2, true><<<N, 64, 0, stream>>>(h2lin, dinv, rowstart, esrc, b2,
                                            nullptr, out_h, hb, N);

  // decode
  {
    dim3 grid((N + 127) / 128, (N + 127) / 128);
    k_decode<<<grid, 256, 0, stream>>>(hb, out_x1, N);
  }
}